// Round 24
// baseline (160.127 us; speedup 1.0000x reference)
//
#include <hip/hip_runtime.h>
#include <hip/hip_bf16.h>
#include <math.h>

// vec[b,e] = sum_s softmax_s( tanh(theta@w.T [b,:] + h[b,s,:]@u) @ v ) * h[b,s,e]
// B=64, S=2048, E=256, T=100
// R24 = R20's 4-blocks/CU shape + the waves_per_eu pin R20 lacked:
//   - GM=16 rows/chunk -> LDS 37 KB -> 4 blocks/CU, 16 waves/CU (4/SIMD).
//   - 256-thr/4-wave blocks (narrow barriers; R22's 8-wave sync regressed).
//   - amdgpu_waves_per_eu(4,4): register budget pinned to exactly 128.
//     Live set ~75 regs (un 16 + acc 16 + af 4 + misc) -> real slack.
//     (R20 unpinned: allocator targeted 8 waves/EU = 64 regs -> 411MB spill.)
//   - u streamed from L2 per k-step (4 blocks/CU share L2-hot u_t).
//   - R21's pipeline verbatim: counted vmcnt(4), raw s_barrier,
//     register-free global_load_lds staging, involution slot swizzle,
//     self-staged wsum rows (j*4+w), no-max softmax, register num/den.

#define E_DIM 256
#define GM 16        // s-rows per chunk
#define NC 8         // chunks per block

typedef __bf16 bf16x8 __attribute__((ext_vector_type(8)));
typedef float  f32x4  __attribute__((ext_vector_type(4)));

__device__ __forceinline__ unsigned short f2bf(float x) {
    return __builtin_bit_cast(unsigned short, (__bf16)x);
}

// tanh(x) = 1 - 2/(exp(2x)+1); overflow-safe (rcp(inf)=0).
__device__ __forceinline__ float fast_tanh(float x) {
    const float e = __expf(2.0f * x);
    const float r = __builtin_amdgcn_rcpf(e + 1.0f);
    return fmaf(-2.0f, r, 1.0f);
}

// slot swizzle within a 64-slot (16B each) fp32 row: XOR low 4 slot bits
// with row&15. Involution; identical on stage-source and read side.
__device__ __forceinline__ unsigned sswz(unsigned slot, unsigned row) {
    return (slot & 48u) | ((slot & 15u) ^ (row & 15u));
}

// ---------------- Kernel 0 (fused prep): u transpose (coalesced) + theta@w.T ----
__global__ __launch_bounds__(256) void k_prep(const float* __restrict__ u,
                                              const float* __restrict__ theta,
                                              const float* __restrict__ w,
                                              unsigned short* __restrict__ u_t,
                                              float* __restrict__ tw,
                                              int T) {
    if (blockIdx.x < 16) {
        // transpose a 256(e) x 16(f) slab of u into u_t[f][e], coalesced both ways
        __shared__ float tl[256 * 17];   // +1 pad: conflict-free transposed reads
        const int f0 = blockIdx.x * 16;
        const int tid = threadIdx.x;
        const int cl = tid & 15;         // f-col within slab
        const int rw = tid >> 4;         // 0..15
#pragma unroll
        for (int it = 0; it < 16; ++it) {
            const int e = it * 16 + rw;
            tl[e * 17 + cl] = u[(size_t)e * E_DIM + f0 + cl];
        }
        __syncthreads();
        unsigned short outv[16];
#pragma unroll
        for (int j = 0; j < 16; ++j)
            outv[j] = f2bf(tl[(cl * 16 + j) * 17 + rw]);
        *reinterpret_cast<uint4*>(u_t + (size_t)(f0 + rw) * E_DIM + cl * 16) =
            *reinterpret_cast<const uint4*>(outv);
        *reinterpret_cast<uint4*>(u_t + (size_t)(f0 + rw) * E_DIM + cl * 16 + 8) =
            *reinterpret_cast<const uint4*>(outv + 8);
    } else {
        __shared__ float th[128];
        const int b = blockIdx.x - 16;
        const int e = threadIdx.x;
        if (threadIdx.x < T) th[threadIdx.x] = theta[b * T + threadIdx.x];
        __syncthreads();
        float acc = 0.f;
        for (int t = 0; t < T; ++t) acc = fmaf(th[t], w[e * T + t], acc);
        tw[b * E_DIM + e] = acc;
    }
}

// ---------------- Kernel 1 (fused, 4 blocks/CU, counted vmcnt) ----------------
__global__
__attribute__((amdgpu_flat_work_group_size(256, 256), amdgpu_waves_per_eu(4, 4)))
void k_fused(const float* __restrict__ h,
             const unsigned short* __restrict__ u_t,
             const float* __restrict__ tw_,
             const float* __restrict__ v,
             float* __restrict__ partial,
             float* __restrict__ pd,
             int S, int SC) {
    __shared__ float Abuf[2][GM * E_DIM];   // 2 x 16 KB fp32, slot-swizzled
    __shared__ float red[4][GM];            // 256 B
    __shared__ float pacc[4][E_DIM];        // 4 KB
    __shared__ float dred[4];

    const int b   = blockIdx.y;
    const int c0  = blockIdx.x * NC;        // first chunk for this block
    const int tid = threadIdx.x;
    const int w   = tid >> 6;               // wave 0..3
    const int l   = tid & 63;
    const int lg  = l >> 4;                 // 0..3
    const int lc  = l & 15;                 // 0..15
    const int f0w = w * 64;                 // wave's f-range base

    // stage chunk ch into Abuf[buf]: 4 global_load_lds per WAVE (exact vmcnt
    // count). Wave w stages rows r*4+w. LDS dest linear; source pre-swizzled.
#define STAGE(buf, ch)                                                           \
    {                                                                            \
        const char* hb_ = (const char*)(h + ((size_t)b * S + (size_t)(ch) * GM) * E_DIM); \
        _Pragma("unroll")                                                        \
        for (int r = 0; r < 4; ++r) {                                            \
            const int row = r * 4 + w;                                           \
            const unsigned ss = sswz((unsigned)l, (unsigned)row);                \
            __builtin_amdgcn_global_load_lds(                                    \
                (const __attribute__((address_space(1))) void*)(hb_ + (size_t)row * 1024 + ss * 16), \
                (__attribute__((address_space(3))) void*)((char*)Abuf[buf] + r * 4096 + w * 1024), \
                16, 0, 0);                                                       \
        }                                                                        \
    }

    // ---- prologue: stage chunk 0 (HBM), epilogue constants ----
    STAGE(0, c0);

    const unsigned short* ubase = u_t + (size_t)(f0w + lc) * E_DIM + lg * 8;

    float tw_f[4], v_f[4];
#pragma unroll
    for (int n = 0; n < 4; ++n) {
        const int f = f0w + n * 16 + lc;
        tw_f[n] = tw_[b * E_DIM + f];
        v_f[n]  = v[f];
    }

    f32x4 numa = (f32x4){0.f, 0.f, 0.f, 0.f};   // running weighted sum, e=l*4..+3
    float den = 0.f;                             // running denominator (wave rows)

    for (int c = 0; c < NC; ++c) {
        const int cur = c & 1;

        // ---- issue stage c+1; wait ONLY for stage c (counted vmcnt) ----
        if (c + 1 < NC) {
            STAGE(cur ^ 1, c0 + c + 1);
            asm volatile("s_waitcnt vmcnt(4)" ::: "memory");
        } else {
            asm volatile("s_waitcnt vmcnt(0)" ::: "memory");
        }
        __builtin_amdgcn_s_barrier();
        __builtin_amdgcn_sched_barrier(0);

        // ---- K loop on Abuf[cur]: u streamed from L2 per k-step ----
        const char* A = (const char*)Abuf[cur];
        f32x4 acc[4];   // [n]; wave covers rows 0..15 x f-cols f0w..f0w+63
#pragma unroll
        for (int n = 0; n < 4; ++n)
            acc[n] = (f32x4){0.f, 0.f, 0.f, 0.f};

#pragma unroll
        for (int kt = 0; kt < 8; ++kt) {
            bf16x8 un[4];
#pragma unroll
            for (int n = 0; n < 4; ++n)
                un[n] = *reinterpret_cast<const bf16x8*>(ubase + (size_t)n * 16 * E_DIM + kt * 32);

            bf16x8 af;
            {
                const unsigned row = (unsigned)lc;
                const unsigned s0 = sswz((unsigned)(kt * 8 + lg * 2), row);
                const unsigned s1 = sswz((unsigned)(kt * 8 + lg * 2 + 1), row);
                const f32x4 fa0 = *reinterpret_cast<const f32x4*>(A + row * 1024 + s0 * 16);
                const f32x4 fa1 = *reinterpret_cast<const f32x4*>(A + row * 1024 + s1 * 16);
#pragma unroll
                for (int j = 0; j < 4; ++j) {
                    af[j]     = (__bf16)fa0[j];
                    af[4 + j] = (__bf16)fa1[j];
                }
            }
#pragma unroll
            for (int n = 0; n < 4; ++n)
                acc[n] = __builtin_amdgcn_mfma_f32_16x16x32_bf16(af, un[n], acc[n], 0, 0, 0);
        }

        // ---- gate epilogue: tanh(z+tw)*v, reduce over f (lc classes) ----
        float rs[4] = {};   // [i]; row = lg*4 + i
#pragma unroll
        for (int n = 0; n < 4; ++n)
#pragma unroll
            for (int i = 0; i < 4; ++i)
                rs[i] += fast_tanh(acc[n][i] + tw_f[n]) * v_f[n];

#pragma unroll
        for (int off = 1; off < 16; off <<= 1)
#pragma unroll
            for (int i = 0; i < 4; ++i)
                rs[i] += __shfl_xor(rs[i], off, 64);

        if (lc == 0) {
#pragma unroll
            for (int i = 0; i < 4; ++i)
                red[w][lg * 4 + i] = rs[i];
        }
        asm volatile("s_waitcnt lgkmcnt(0)" ::: "memory");
        __builtin_amdgcn_s_barrier();   // B2: red ready; all K-loop reads of Abuf[cur] done
        __builtin_amdgcn_sched_barrier(0);

        // ---- fused softmax(no-max) + weighted accumulate, SELF-STAGED rows ----
        // wave w owns rows j*4+w (exactly the rows it stages) -> its own later
        // STAGE is the only writer; hv consumption orders the reads first.
#pragma unroll
        for (int j = 0; j < 4; ++j) {
            const unsigned row = (unsigned)(j * 4 + w);
            const float g = red[0][row] + red[1][row] + red[2][row] + red[3][row];
            const float ex = __expf(g);          // |g| <= sum|v_f| ~ 10.3: safe
            den += ex;
            const unsigned ss = sswz((unsigned)l, row);
            const f32x4 hv = *reinterpret_cast<const f32x4*>(A + row * 1024 + ss * 16);
            numa[0] = fmaf(ex, hv[0], numa[0]);
            numa[1] = fmaf(ex, hv[1], numa[1]);
            numa[2] = fmaf(ex, hv[2], numa[2]);
            numa[3] = fmaf(ex, hv[3], numa[3]);
        }
        // no barrier: next STAGE overwrites only this wave's own rows
    }

    // ---- block epilogue: one write of num/den ----
    *reinterpret_cast<f32x4*>(&pacc[w][l * 4]) = numa;
    if (l == 0) dred[w] = den;
    __syncthreads();

    const int nb = SC / NC;                 // blocks per b (16)
    partial[((size_t)b * nb + blockIdx.x) * E_DIM + tid] =
        pacc[0][tid] + pacc[1][tid] + pacc[2][tid] + pacc[3][tid];
    if (tid == 0)
        pd[(size_t)b * nb + blockIdx.x] = dred[0] + dred[1] + dred[2] + dred[3];
#undef STAGE
}

// ---------------- Kernel 2: merge across blocks (no-max softmax: plain sums) ----
__global__ __launch_bounds__(256) void k_combine(const float* __restrict__ partial,
                                                 const float* __restrict__ pd,
                                                 float* __restrict__ out,
                                                 int NB) {
    const int b = blockIdx.x, t = threadIdx.x;
    float den = 0.f;
    for (int k = 0; k < NB; ++k) den += pd[(size_t)b * NB + k];
    float num = 0.f;
    for (int k = 0; k < NB; ++k)
        num += partial[((size_t)b * NB + k) * E_DIM + t];
    out[(size_t)b * E_DIM + t] = num / den;
}

extern "C" void kernel_launch(void* const* d_in, const int* in_sizes, int n_in,
                              void* d_out, int out_size, void* d_ws, size_t ws_size,
                              hipStream_t stream) {
    const float* h     = (const float*)d_in[0];
    const float* theta = (const float*)d_in[1];
    const float* w     = (const float*)d_in[2];
    const float* v     = (const float*)d_in[3];
    const float* u     = (const float*)d_in[4];
    float* out = (float*)d_out;

    const int E = in_sizes[3];              // 256
    const int T = in_sizes[2] / E;          // 100
    const int B = in_sizes[1] / T;          // 64
    const int S = in_sizes[0] / (B * E);    // 2048
    const int SC = S / GM;                  // 128
    const int NB = SC / NC;                 // 16 blocks per b

    float* tw = (float*)d_ws;                                     // [B,E]
    unsigned short* u_t = (unsigned short*)(tw + (size_t)B * E);  // [E,E] bf16
    float* partial = (float*)(u_t + (size_t)E * E);               // [B,NB,E]
    float* pd = partial + (size_t)B * NB * E;                     // [B,NB]

    k_prep<<<dim3(16 + B), dim3(256), 0, stream>>>(u, theta, w, u_t, tw, T);
    k_fused<<<dim3(NB, B), dim3(256), 0, stream>>>(h, u_t, tw, v, partial, pd, S, SC);
    k_combine<<<dim3(B), dim3(256), 0, stream>>>(partial, pd, out, NB);
}

// Round 25
// 142.807 us; speedup vs baseline: 1.1213x; 1.1213x over previous
//
#include <hip/hip_runtime.h>
#include <hip/hip_bf16.h>
#include <math.h>

// vec[b,e] = sum_s softmax_s( tanh(theta@w.T [b,:] + h[b,s,:]@u) @ v ) * h[b,s,e]
// B=64, S=2048, E=256, T=100
// R25 = R24 redesigned FOR the 64-VGPR budget the allocator actually grants
//       (R24 overshot by ~11 regs -> 27MB scratch):
//   - tw/v moved to LDS (2 KB, loaded once per block): -8 VGPRs.
//   - plain __launch_bounds__(256); live set ~59 <= 64 -> no spill.
//   - GM=16, LDS 39.4 KB -> 4 blocks/CU = 16 waves/CU = 4 waves/SIMD
//     (2x R21's latency hiding at identical traffic).
//   - rest = R21/R24 verbatim: counted vmcnt(4), register-free global_load_lds
//     staging, involution slot swizzle, self-staged wsum rows (j*4+w),
//     no-max softmax, register num/den accumulation.

#define E_DIM 256
#define GM 16        // s-rows per chunk
#define NC 8         // chunks per block

typedef __bf16 bf16x8 __attribute__((ext_vector_type(8)));
typedef float  f32x4  __attribute__((ext_vector_type(4)));

__device__ __forceinline__ unsigned short f2bf(float x) {
    return __builtin_bit_cast(unsigned short, (__bf16)x);
}

// tanh(x) = 1 - 2/(exp(2x)+1); overflow-safe (rcp(inf)=0).
__device__ __forceinline__ float fast_tanh(float x) {
    const float e = __expf(2.0f * x);
    const float r = __builtin_amdgcn_rcpf(e + 1.0f);
    return fmaf(-2.0f, r, 1.0f);
}

// slot swizzle within a 64-slot (16B each) fp32 row: XOR low 4 slot bits
// with row&15. Involution; identical on stage-source and read side.
__device__ __forceinline__ unsigned sswz(unsigned slot, unsigned row) {
    return (slot & 48u) | ((slot & 15u) ^ (row & 15u));
}

// ---------------- Kernel 0 (fused prep): u transpose (coalesced) + theta@w.T ----
__global__ __launch_bounds__(256) void k_prep(const float* __restrict__ u,
                                              const float* __restrict__ theta,
                                              const float* __restrict__ w,
                                              unsigned short* __restrict__ u_t,
                                              float* __restrict__ tw,
                                              int T) {
    if (blockIdx.x < 16) {
        // transpose a 256(e) x 16(f) slab of u into u_t[f][e], coalesced both ways
        __shared__ float tl[256 * 17];   // +1 pad: conflict-free transposed reads
        const int f0 = blockIdx.x * 16;
        const int tid = threadIdx.x;
        const int cl = tid & 15;         // f-col within slab
        const int rw = tid >> 4;         // 0..15
#pragma unroll
        for (int it = 0; it < 16; ++it) {
            const int e = it * 16 + rw;
            tl[e * 17 + cl] = u[(size_t)e * E_DIM + f0 + cl];
        }
        __syncthreads();
        unsigned short outv[16];
#pragma unroll
        for (int j = 0; j < 16; ++j)
            outv[j] = f2bf(tl[(cl * 16 + j) * 17 + rw]);
        *reinterpret_cast<uint4*>(u_t + (size_t)(f0 + rw) * E_DIM + cl * 16) =
            *reinterpret_cast<const uint4*>(outv);
        *reinterpret_cast<uint4*>(u_t + (size_t)(f0 + rw) * E_DIM + cl * 16 + 8) =
            *reinterpret_cast<const uint4*>(outv + 8);
    } else {
        __shared__ float th[128];
        const int b = blockIdx.x - 16;
        const int e = threadIdx.x;
        if (threadIdx.x < T) th[threadIdx.x] = theta[b * T + threadIdx.x];
        __syncthreads();
        float acc = 0.f;
        for (int t = 0; t < T; ++t) acc = fmaf(th[t], w[e * T + t], acc);
        tw[b * E_DIM + e] = acc;
    }
}

// ---------------- Kernel 1 (fused, 4 blocks/CU, 64-VGPR budget) ----------------
__global__ __launch_bounds__(256) void k_fused(const float* __restrict__ h,
                                               const unsigned short* __restrict__ u_t,
                                               const float* __restrict__ tw_,
                                               const float* __restrict__ v,
                                               float* __restrict__ partial,
                                               float* __restrict__ pd,
                                               int S, int SC) {
    __shared__ float Abuf[2][GM * E_DIM];   // 2 x 16 KB fp32, slot-swizzled
    __shared__ float red[4][GM];            // 256 B
    __shared__ float pacc[4][E_DIM];        // 4 KB
    __shared__ float twl[E_DIM];            // 1 KB  (tw[b,:])
    __shared__ float vl[E_DIM];             // 1 KB  (v)
    __shared__ float dred[4];

    const int b   = blockIdx.y;
    const int c0  = blockIdx.x * NC;        // first chunk for this block
    const int tid = threadIdx.x;
    const int w   = tid >> 6;               // wave 0..3
    const int l   = tid & 63;
    const int lg  = l >> 4;                 // 0..3
    const int lc  = l & 15;                 // 0..15
    const int f0w = w * 64;                 // wave's f-range base

    // stage chunk ch into Abuf[buf]: 4 global_load_lds per WAVE (exact vmcnt
    // count). Wave w stages rows r*4+w. LDS dest linear; source pre-swizzled.
#define STAGE(buf, ch)                                                           \
    {                                                                            \
        const char* hb_ = (const char*)(h + ((size_t)b * S + (size_t)(ch) * GM) * E_DIM); \
        _Pragma("unroll")                                                        \
        for (int r = 0; r < 4; ++r) {                                            \
            const int row = r * 4 + w;                                           \
            const unsigned ss = sswz((unsigned)l, (unsigned)row);                \
            __builtin_amdgcn_global_load_lds(                                    \
                (const __attribute__((address_space(1))) void*)(hb_ + (size_t)row * 1024 + ss * 16), \
                (__attribute__((address_space(3))) void*)((char*)Abuf[buf] + r * 4096 + w * 1024), \
                16, 0, 0);                                                       \
        }                                                                        \
    }

    // ---- prologue: stage chunk 0 (HBM); tw/v -> LDS (saves 8 VGPRs) ----
    STAGE(0, c0);
    twl[tid] = tw_[(size_t)b * E_DIM + tid];
    vl[tid]  = v[tid];
    __syncthreads();   // publishes twl/vl (and drains stage 0 - once per block)

    const unsigned short* ubase = u_t + (size_t)(f0w + lc) * E_DIM + lg * 8;

    f32x4 numa = (f32x4){0.f, 0.f, 0.f, 0.f};   // running weighted sum, e=l*4..+3
    float den = 0.f;                             // running denominator (wave rows)

    for (int c = 0; c < NC; ++c) {
        const int cur = c & 1;

        // ---- issue stage c+1; wait ONLY for stage c (counted vmcnt) ----
        if (c + 1 < NC) {
            STAGE(cur ^ 1, c0 + c + 1);
            asm volatile("s_waitcnt vmcnt(4)" ::: "memory");
        } else {
            asm volatile("s_waitcnt vmcnt(0)" ::: "memory");
        }
        __builtin_amdgcn_s_barrier();
        __builtin_amdgcn_sched_barrier(0);

        // ---- K loop on Abuf[cur]: u streamed from L2 per k-step ----
        const char* A = (const char*)Abuf[cur];
        f32x4 acc[4];   // [n]; wave covers rows 0..15 x f-cols f0w..f0w+63
#pragma unroll
        for (int n = 0; n < 4; ++n)
            acc[n] = (f32x4){0.f, 0.f, 0.f, 0.f};

#pragma unroll
        for (int kt = 0; kt < 8; ++kt) {
            bf16x8 un[4];
#pragma unroll
            for (int n = 0; n < 4; ++n)
                un[n] = *reinterpret_cast<const bf16x8*>(ubase + (size_t)n * 16 * E_DIM + kt * 32);

            bf16x8 af;
            {
                const unsigned row = (unsigned)lc;
                const unsigned s0 = sswz((unsigned)(kt * 8 + lg * 2), row);
                const unsigned s1 = sswz((unsigned)(kt * 8 + lg * 2 + 1), row);
                const f32x4 fa0 = *reinterpret_cast<const f32x4*>(A + row * 1024 + s0 * 16);
                const f32x4 fa1 = *reinterpret_cast<const f32x4*>(A + row * 1024 + s1 * 16);
#pragma unroll
                for (int j = 0; j < 4; ++j) {
                    af[j]     = (__bf16)fa0[j];
                    af[4 + j] = (__bf16)fa1[j];
                }
            }
#pragma unroll
            for (int n = 0; n < 4; ++n)
                acc[n] = __builtin_amdgcn_mfma_f32_16x16x32_bf16(af, un[n], acc[n], 0, 0, 0);
        }

        // ---- gate epilogue: tanh(z+tw)*v from LDS consts, reduce over f ----
        float rs[4] = {};   // [i]; row = lg*4 + i
#pragma unroll
        for (int n = 0; n < 4; ++n) {
            const int f = f0w + n * 16 + lc;
            const float tw_n = twl[f];
            const float v_n  = vl[f];
#pragma unroll
            for (int i = 0; i < 4; ++i)
                rs[i] += fast_tanh(acc[n][i] + tw_n) * v_n;
        }

#pragma unroll
        for (int off = 1; off < 16; off <<= 1)
#pragma unroll
            for (int i = 0; i < 4; ++i)
                rs[i] += __shfl_xor(rs[i], off, 64);

        if (lc == 0) {
#pragma unroll
            for (int i = 0; i < 4; ++i)
                red[w][lg * 4 + i] = rs[i];
        }
        asm volatile("s_waitcnt lgkmcnt(0)" ::: "memory");
        __builtin_amdgcn_s_barrier();   // B2: red ready; all K-loop reads of Abuf[cur] done
        __builtin_amdgcn_sched_barrier(0);

        // ---- fused softmax(no-max) + weighted accumulate, SELF-STAGED rows ----
        // wave w owns rows j*4+w (exactly the rows it stages) -> its own later
        // STAGE is the only writer; hv consumption orders the reads first.
#pragma unroll
        for (int j = 0; j < 4; ++j) {
            const unsigned row = (unsigned)(j * 4 + w);
            const float g = red[0][row] + red[1][row] + red[2][row] + red[3][row];
            const float ex = __expf(g);          // |g| <= sum|v_f| ~ 10.3: safe
            den += ex;
            const unsigned ss = sswz((unsigned)l, row);
            const f32x4 hv = *reinterpret_cast<const f32x4*>(A + row * 1024 + ss * 16);
            numa[0] = fmaf(ex, hv[0], numa[0]);
            numa[1] = fmaf(ex, hv[1], numa[1]);
            numa[2] = fmaf(ex, hv[2], numa[2]);
            numa[3] = fmaf(ex, hv[3], numa[3]);
        }
        // no barrier: next STAGE overwrites only this wave's own rows
    }

    // ---- block epilogue: one write of num/den ----
    *reinterpret_cast<f32x4*>(&pacc[w][l * 4]) = numa;
    if (l == 0) dred[w] = den;
    __syncthreads();

    const int nb = SC / NC;                 // blocks per b (16)
    partial[((size_t)b * nb + blockIdx.x) * E_DIM + tid] =
        pacc[0][tid] + pacc[1][tid] + pacc[2][tid] + pacc[3][tid];
    if (tid == 0)
        pd[(size_t)b * nb + blockIdx.x] = dred[0] + dred[1] + dred[2] + dred[3];
#undef STAGE
}

// ---------------- Kernel 2: merge across blocks (no-max softmax: plain sums) ----
__global__ __launch_bounds__(256) void k_combine(const float* __restrict__ partial,
                                                 const float* __restrict__ pd,
                                                 float* __restrict__ out,
                                                 int NB) {
    const int b = blockIdx.x, t = threadIdx.x;
    float den = 0.f;
    for (int k = 0; k < NB; ++k) den += pd[(size_t)b * NB + k];
    float num = 0.f;
    for (int k = 0; k < NB; ++k)
        num += partial[((size_t)b * NB + k) * E_DIM + t];
    out[(size_t)b * E_DIM + t] = num / den;
}

extern "C" void kernel_launch(void* const* d_in, const int* in_sizes, int n_in,
                              void* d_out, int out_size, void* d_ws, size_t ws_size,
                              hipStream_t stream) {
    const float* h     = (const float*)d_in[0];
    const float* theta = (const float*)d_in[1];
    const float* w     = (const float*)d_in[2];
    const float* v     = (const float*)d_in[3];
    const float* u     = (const float*)d_in[4];
    float* out = (float*)d_out;

    const int E = in_sizes[3];              // 256
    const int T = in_sizes[2] / E;          // 100
    const int B = in_sizes[1] / T;          // 64
    const int S = in_sizes[0] / (B * E);    // 2048
    const int SC = S / GM;                  // 128
    const int NB = SC / NC;                 // 16 blocks per b

    float* tw = (float*)d_ws;                                     // [B,E]
    unsigned short* u_t = (unsigned short*)(tw + (size_t)B * E);  // [E,E] bf16
    float* partial = (float*)(u_t + (size_t)E * E);               // [B,NB,E]
    float* pd = partial + (size_t)B * NB * E;                     // [B,NB]

    k_prep<<<dim3(16 + B), dim3(256), 0, stream>>>(u, theta, w, u_t, tw, T);
    k_fused<<<dim3(NB, B), dim3(256), 0, stream>>>(h, u_t, tw, v, partial, pd, S, SC);
    k_combine<<<dim3(B), dim3(256), 0, stream>>>(partial, pd, out, NB);
}

// Round 26
// 128.082 us; speedup vs baseline: 1.2502x; 1.1150x over previous
//
#include <hip/hip_runtime.h>
#include <hip/hip_bf16.h>
#include <math.h>

// vec[b,e] = sum_s softmax_s( tanh(theta@w.T [b,:] + h[b,s,:]@u) @ v ) * h[b,s,e]
// B=64, S=2048, E=256, T=100
// R26 = R21's k_fused chunk loop (57.7us best) + end-to-end consolidation:
//   - k_combine ELIMINATED: blocks atomicAdd num/den into d_ws accumulators;
//     ticket pattern (release threadfence + device atomics) lets the last
//     block per b write out = num/den. One less launch + gap + round-trip.
//   - tw computed inside k_fused prologue (100 FMA/thread, hidden under the
//     u-hoist VMEM latency) -> k_prep shrinks to u-transpose + zeroing the
//     accumulators (d_ws is not re-poisoned between replays).
//   - chunk loop byte-identical to R21: counted vmcnt(8), register-free
//     global_load_lds staging, involution swizzle, u-hoist 128 VGPR,
//     self-staged wsum rows, no-max softmax, register num/den, (2,2) pin.

#define E_DIM 256
#define GM 32        // s-rows per chunk
#define NC 8         // chunks per block
#define NB 8         // blocks per b (SC/NC)

typedef __bf16 bf16x8 __attribute__((ext_vector_type(8)));
typedef float  f32x4  __attribute__((ext_vector_type(4)));

__device__ __forceinline__ unsigned short f2bf(float x) {
    return __builtin_bit_cast(unsigned short, (__bf16)x);
}

// tanh(x) = 1 - 2/(exp(2x)+1); overflow-safe (rcp(inf)=0).
__device__ __forceinline__ float fast_tanh(float x) {
    const float e = __expf(2.0f * x);
    const float r = __builtin_amdgcn_rcpf(e + 1.0f);
    return fmaf(-2.0f, r, 1.0f);
}

// slot swizzle within a 64-slot (16B each) fp32 row: XOR low 4 slot bits
// with row&15. Involution; identical on stage-source and read side.
__device__ __forceinline__ unsigned sswz(unsigned slot, unsigned row) {
    return (slot & 48u) | ((slot & 15u) ^ (row & 15u));
}

// ---------------- Kernel 0: u transpose (coalesced) + accumulator zeroing ----
__global__ __launch_bounds__(256) void k_prep(const float* __restrict__ u,
                                              unsigned short* __restrict__ u_t,
                                              float* __restrict__ num_acc,
                                              float* __restrict__ den_acc,
                                              int* __restrict__ ticket) {
    if (blockIdx.x < 16) {
        // transpose a 256(e) x 16(f) slab of u into u_t[f][e], coalesced both ways
        __shared__ float tl[256 * 17];   // +1 pad: conflict-free transposed reads
        const int f0 = blockIdx.x * 16;
        const int tid = threadIdx.x;
        const int cl = tid & 15;         // f-col within slab
        const int rw = tid >> 4;         // 0..15
#pragma unroll
        for (int it = 0; it < 16; ++it) {
            const int e = it * 16 + rw;
            tl[e * 17 + cl] = u[(size_t)e * E_DIM + f0 + cl];
        }
        __syncthreads();
        unsigned short outv[16];
#pragma unroll
        for (int j = 0; j < 16; ++j)
            outv[j] = f2bf(tl[(cl * 16 + j) * 17 + rw]);
        *reinterpret_cast<uint4*>(u_t + (size_t)(f0 + rw) * E_DIM + cl * 16) =
            *reinterpret_cast<const uint4*>(outv);
        *reinterpret_cast<uint4*>(u_t + (size_t)(f0 + rw) * E_DIM + cl * 16 + 8) =
            *reinterpret_cast<const uint4*>(outv + 8);
    } else {
        // zero this b's accumulators (d_ws is not re-poisoned between replays)
        const int b = blockIdx.x - 16;
        num_acc[(size_t)b * E_DIM + threadIdx.x] = 0.f;
        if (threadIdx.x == 0) {
            den_acc[b] = 0.f;
            ticket[b] = 0;
        }
    }
}

// ---------------- Kernel 1 (fused gate+softmax+wsum+combine) ----------------
__global__
__attribute__((amdgpu_flat_work_group_size(256, 256), amdgpu_waves_per_eu(2, 2)))
void k_fused(const float* __restrict__ h,
             const unsigned short* __restrict__ u_t,
             const float* __restrict__ theta,
             const float* __restrict__ wm,
             const float* __restrict__ v,
             float* __restrict__ num_acc,
             float* __restrict__ den_acc,
             int* __restrict__ ticket,
             float* __restrict__ out,
             int S, int SC, int T) {
    __shared__ float Abuf[2][GM * E_DIM];   // 2 x 32 KB fp32, slot-swizzled
    __shared__ float red[4][GM];            // 512 B
    __shared__ float pacc[4][E_DIM];        // 4 KB
    __shared__ float twl[E_DIM];            // 1 KB
    __shared__ float dred[4];
    __shared__ int lastFlag;

    const int b   = blockIdx.y;
    const int c0  = blockIdx.x * NC;        // first chunk for this block
    const int tid = threadIdx.x;
    const int w   = tid >> 6;               // wave 0..3
    const int l   = tid & 63;
    const int lg  = l >> 4;                 // 0..3
    const int lc  = l & 15;                 // 0..15
    const int f0w = w * 64;                 // wave's f-range base

    // stage chunk ch into Abuf[buf]: 8 global_load_lds per WAVE (exact vmcnt
    // count). Wave w stages rows r*4+w. LDS dest linear; source pre-swizzled.
#define STAGE(buf, ch)                                                           \
    {                                                                            \
        const char* hb_ = (const char*)(h + ((size_t)b * S + (size_t)(ch) * GM) * E_DIM); \
        _Pragma("unroll")                                                        \
        for (int r = 0; r < 8; ++r) {                                            \
            const int row = r * 4 + w;                                           \
            const unsigned ss = sswz((unsigned)l, (unsigned)row);                \
            __builtin_amdgcn_global_load_lds(                                    \
                (const __attribute__((address_space(1))) void*)(hb_ + (size_t)row * 1024 + ss * 16), \
                (__attribute__((address_space(3))) void*)((char*)Abuf[buf] + r * 4096 + w * 1024), \
                16, 0, 0);                                                       \
        }                                                                        \
    }

    // ---- prologue: stage chunk 0 (HBM) + u-hoist (L2) + tw compute (VALU) ----
    STAGE(0, c0);

    bf16x8 ub[8][4];   // [kt][n]  (128 VGPR, amortized over NC chunks)
#pragma unroll
    for (int kt = 0; kt < 8; ++kt)
#pragma unroll
        for (int n = 0; n < 4; ++n)
            ub[kt][n] = *reinterpret_cast<const bf16x8*>(
                u_t + (size_t)(f0w + n * 16 + lc) * E_DIM + kt * 32 + lg * 8);

    // tw[b][tid] = sum_t theta[b,t] * w[tid,t]  (VALU work under VMEM latency)
    {
        float acc = 0.f;
        const float* thr = theta + (size_t)b * T;
        const float* wr  = wm + (size_t)tid * T;
        for (int t = 0; t < T; ++t) acc = fmaf(thr[t], wr[t], acc);
        twl[tid] = acc;
    }
    __syncthreads();   // drains vmcnt(0) (stage 0 + ub) and publishes twl

    float tw_f[4], v_f[4];
#pragma unroll
    for (int n = 0; n < 4; ++n) {
        const int f = f0w + n * 16 + lc;
        tw_f[n] = twl[f];
        v_f[n]  = v[f];
    }

    f32x4 numa = (f32x4){0.f, 0.f, 0.f, 0.f};   // running weighted sum, e=l*4..+3
    float den = 0.f;                             // running denominator (wave rows)

    for (int c = 0; c < NC; ++c) {
        const int cur = c & 1;

        // ---- issue stage c+1; wait ONLY for stage c (counted vmcnt) ----
        if (c + 1 < NC) {
            STAGE(cur ^ 1, c0 + c + 1);
            asm volatile("s_waitcnt vmcnt(8)" ::: "memory");
        } else {
            asm volatile("s_waitcnt vmcnt(0)" ::: "memory");
        }
        __builtin_amdgcn_s_barrier();
        __builtin_amdgcn_sched_barrier(0);

        // ---- K loop on Abuf[cur]: pure LDS + cvt + MFMA ----
        const char* A = (const char*)Abuf[cur];
        f32x4 acc[2][4];
#pragma unroll
        for (int m = 0; m < 2; ++m)
#pragma unroll
            for (int n = 0; n < 4; ++n)
                acc[m][n] = (f32x4){0.f, 0.f, 0.f, 0.f};

#pragma unroll
        for (int kt = 0; kt < 8; ++kt) {
            bf16x8 af[2];
#pragma unroll
            for (int m = 0; m < 2; ++m) {
                const unsigned row = (unsigned)(m * 16 + lc);
                const unsigned s0 = sswz((unsigned)(kt * 8 + lg * 2), row);
                const unsigned s1 = sswz((unsigned)(kt * 8 + lg * 2 + 1), row);
                const f32x4 fa0 = *reinterpret_cast<const f32x4*>(A + row * 1024 + s0 * 16);
                const f32x4 fa1 = *reinterpret_cast<const f32x4*>(A + row * 1024 + s1 * 16);
#pragma unroll
                for (int j = 0; j < 4; ++j) {
                    af[m][j]     = (__bf16)fa0[j];
                    af[m][4 + j] = (__bf16)fa1[j];
                }
            }
#pragma unroll
            for (int n = 0; n < 4; ++n) {
                acc[0][n] = __builtin_amdgcn_mfma_f32_16x16x32_bf16(af[0], ub[kt][n], acc[0][n], 0, 0, 0);
                acc[1][n] = __builtin_amdgcn_mfma_f32_16x16x32_bf16(af[1], ub[kt][n], acc[1][n], 0, 0, 0);
            }
        }

        // ---- gate epilogue: tanh(z+tw)*v, reduce over f (lc classes) ----
        float rs[2][4] = {};   // [m][i]; row = m*16 + lg*4 + i
#pragma unroll
        for (int n = 0; n < 4; ++n)
#pragma unroll
            for (int m = 0; m < 2; ++m)
#pragma unroll
                for (int i = 0; i < 4; ++i)
                    rs[m][i] += fast_tanh(acc[m][n][i] + tw_f[n]) * v_f[n];

#pragma unroll
        for (int off = 1; off < 16; off <<= 1)
#pragma unroll
            for (int m = 0; m < 2; ++m)
#pragma unroll
                for (int i = 0; i < 4; ++i)
                    rs[m][i] += __shfl_xor(rs[m][i], off, 64);

        if (lc == 0) {
#pragma unroll
            for (int m = 0; m < 2; ++m)
#pragma unroll
                for (int i = 0; i < 4; ++i)
                    red[w][m * 16 + lg * 4 + i] = rs[m][i];
        }
        asm volatile("s_waitcnt lgkmcnt(0)" ::: "memory");
        __builtin_amdgcn_s_barrier();   // B2: red ready; all K-loop reads of Abuf[cur] done
        __builtin_amdgcn_sched_barrier(0);

        // ---- fused softmax(no-max) + weighted accumulate, SELF-STAGED rows ----
#pragma unroll
        for (int j = 0; j < 8; ++j) {
            const unsigned row = (unsigned)(j * 4 + w);
            const float g = red[0][row] + red[1][row] + red[2][row] + red[3][row];
            const float ex = __expf(g);          // |g| <= sum|v_f| ~ 10.3: safe
            den += ex;
            const unsigned ss = sswz((unsigned)l, row);
            const f32x4 hv = *reinterpret_cast<const f32x4*>(A + row * 1024 + ss * 16);
            numa[0] = fmaf(ex, hv[0], numa[0]);
            numa[1] = fmaf(ex, hv[1], numa[1]);
            numa[2] = fmaf(ex, hv[2], numa[2]);
            numa[3] = fmaf(ex, hv[3], numa[3]);
        }
        // no barrier: next STAGE overwrites only this wave's own rows
    }

    // ---- block epilogue: reduce across waves, atomic-combine across blocks ----
    *reinterpret_cast<f32x4*>(&pacc[w][l * 4]) = numa;
    if (l == 0) dred[w] = den;
    __syncthreads();

    const float mysum = pacc[0][tid] + pacc[1][tid] + pacc[2][tid] + pacc[3][tid];
    atomicAdd(&num_acc[(size_t)b * E_DIM + tid], mysum);
    if (tid == 0)
        atomicAdd(&den_acc[b], dred[0] + dred[1] + dred[2] + dred[3]);
    __threadfence();   // release: our adds visible before ticket increment

    if (tid == 0) {
        const int old = atomicAdd(&ticket[b], 1);
        lastFlag = (old == NB - 1);
    }
    __syncthreads();

    if (lastFlag) {
        __threadfence();   // acquire: see all other blocks' adds
        const float nsum = atomicAdd(&num_acc[(size_t)b * E_DIM + tid], 0.f);
        float dsum;
        if (tid == 0) dred[0] = atomicAdd(&den_acc[b], 0.f);
        __syncthreads();
        dsum = dred[0];
        out[(size_t)b * E_DIM + tid] = nsum / dsum;
    }
#undef STAGE
}

extern "C" void kernel_launch(void* const* d_in, const int* in_sizes, int n_in,
                              void* d_out, int out_size, void* d_ws, size_t ws_size,
                              hipStream_t stream) {
    const float* h     = (const float*)d_in[0];
    const float* theta = (const float*)d_in[1];
    const float* w     = (const float*)d_in[2];
    const float* v     = (const float*)d_in[3];
    const float* u     = (const float*)d_in[4];
    float* out = (float*)d_out;

    const int E = in_sizes[3];              // 256
    const int T = in_sizes[2] / E;          // 100
    const int B = in_sizes[1] / T;          // 64
    const int S = in_sizes[0] / (B * E);    // 2048
    const int SC = S / GM;                  // 64

    unsigned short* u_t = (unsigned short*)d_ws;                  // [E,E] bf16
    float* num_acc = (float*)(u_t + (size_t)E * E);               // [B,E]
    float* den_acc = num_acc + (size_t)B * E;                     // [B]
    int*   ticket  = (int*)(den_acc + B);                         // [B]

    k_prep<<<dim3(16 + B), dim3(256), 0, stream>>>(u, u_t, num_acc, den_acc, ticket);
    k_fused<<<dim3(NB, B), dim3(256), 0, stream>>>(h, u_t, theta, w, v,
                                                   num_acc, den_acc, ticket, out, S, SC, T);
}

// Round 27
// 54.424 us; speedup vs baseline: 2.9422x; 2.3534x over previous
//
#include <hip/hip_runtime.h>
#include <hip/hip_bf16.h>
#include <math.h>

// vec[b,e] = sum_s softmax_s( tanh(theta@w.T [b,:] + h[b,s,:]@u) @ v ) * h[b,s,e]
// B=64, S=2048, E=256, T=100
// R27 = byte-identical R21 (57.7us best) + T5 s_setprio around the MFMA
//       cluster and gate epilogue. Register-neutral (SOPP only). R21's
//       counted-vmcnt phase split gives waves different roles (stage-issuing
//       vs MFMA/epilogue) -> scheduler bias pays per m218b (+21-25% on the
//       8-phase GEMM). All other knobs exhausted: occupancy raises spill
//       (R20/R24/R26), u-streaming is latency-bound (R25), barrier cuts
//       neutral (R23).

#define E_DIM 256
#define GM 32        // s-rows per chunk
#define NC 8         // chunks per block

typedef __bf16 bf16x8 __attribute__((ext_vector_type(8)));
typedef float  f32x4  __attribute__((ext_vector_type(4)));

__device__ __forceinline__ unsigned short f2bf(float x) {
    return __builtin_bit_cast(unsigned short, (__bf16)x);
}

// tanh(x) = 1 - 2/(exp(2x)+1); overflow-safe (rcp(inf)=0).
__device__ __forceinline__ float fast_tanh(float x) {
    const float e = __expf(2.0f * x);
    const float r = __builtin_amdgcn_rcpf(e + 1.0f);
    return fmaf(-2.0f, r, 1.0f);
}

// slot swizzle within a 64-slot (16B each) fp32 row: XOR low 4 slot bits
// with row&15. Involution; identical on stage-source and read side.
__device__ __forceinline__ unsigned sswz(unsigned slot, unsigned row) {
    return (slot & 48u) | ((slot & 15u) ^ (row & 15u));
}

// ---------------- Kernel 0 (fused prep): u transpose (coalesced) + theta@w.T ----
__global__ __launch_bounds__(256) void k_prep(const float* __restrict__ u,
                                              const float* __restrict__ theta,
                                              const float* __restrict__ w,
                                              unsigned short* __restrict__ u_t,
                                              float* __restrict__ tw,
                                              int T) {
    if (blockIdx.x < 16) {
        // transpose a 256(e) x 16(f) slab of u into u_t[f][e], coalesced both ways
        __shared__ float tl[256 * 17];   // +1 pad: conflict-free transposed reads
        const int f0 = blockIdx.x * 16;
        const int tid = threadIdx.x;
        const int cl = tid & 15;         // f-col within slab
        const int rw = tid >> 4;         // 0..15
#pragma unroll
        for (int it = 0; it < 16; ++it) {
            const int e = it * 16 + rw;
            tl[e * 17 + cl] = u[(size_t)e * E_DIM + f0 + cl];
        }
        __syncthreads();
        unsigned short outv[16];
#pragma unroll
        for (int j = 0; j < 16; ++j)
            outv[j] = f2bf(tl[(cl * 16 + j) * 17 + rw]);
        *reinterpret_cast<uint4*>(u_t + (size_t)(f0 + rw) * E_DIM + cl * 16) =
            *reinterpret_cast<const uint4*>(outv);
        *reinterpret_cast<uint4*>(u_t + (size_t)(f0 + rw) * E_DIM + cl * 16 + 8) =
            *reinterpret_cast<const uint4*>(outv + 8);
    } else {
        __shared__ float th[128];
        const int b = blockIdx.x - 16;
        const int e = threadIdx.x;
        if (threadIdx.x < T) th[threadIdx.x] = theta[b * T + threadIdx.x];
        __syncthreads();
        float acc = 0.f;
        for (int t = 0; t < T; ++t) acc = fmaf(th[t], w[e * T + t], acc);
        tw[b * E_DIM + e] = acc;
    }
}

// ---------------- Kernel 1 (fused, counted-vmcnt, 2 barriers/chunk) ----------
__global__
__attribute__((amdgpu_flat_work_group_size(256, 256), amdgpu_waves_per_eu(2, 2)))
void k_fused(const float* __restrict__ h,
             const unsigned short* __restrict__ u_t,
             const float* __restrict__ tw_,
             const float* __restrict__ v,
             float* __restrict__ partial,
             float* __restrict__ pd,
             int S, int SC) {
    __shared__ float Abuf[2][GM * E_DIM];   // 2 x 32 KB fp32, slot-swizzled
    __shared__ float red[4][GM];            // 512 B
    __shared__ float pacc[4][E_DIM];        // 4 KB
    __shared__ float dred[4];

    const int b   = blockIdx.y;
    const int c0  = blockIdx.x * NC;        // first chunk for this block
    const int tid = threadIdx.x;
    const int w   = tid >> 6;               // wave 0..3
    const int l   = tid & 63;
    const int lg  = l >> 4;                 // 0..3
    const int lc  = l & 15;                 // 0..15
    const int f0w = w * 64;                 // wave's f-range base

    // stage chunk ch into Abuf[buf]: 8 global_load_lds per WAVE (exact vmcnt
    // count). Wave w stages rows r*4+w. LDS dest linear; source pre-swizzled.
#define STAGE(buf, ch)                                                           \
    {                                                                            \
        const char* hb_ = (const char*)(h + ((size_t)b * S + (size_t)(ch) * GM) * E_DIM); \
        _Pragma("unroll")                                                        \
        for (int r = 0; r < 8; ++r) {                                            \
            const int row = r * 4 + w;                                           \
            const unsigned ss = sswz((unsigned)l, (unsigned)row);                \
            __builtin_amdgcn_global_load_lds(                                    \
                (const __attribute__((address_space(1))) void*)(hb_ + (size_t)row * 1024 + ss * 16), \
                (__attribute__((address_space(3))) void*)((char*)Abuf[buf] + r * 4096 + w * 1024), \
                16, 0, 0);                                                       \
        }                                                                        \
    }

    // ---- prologue: stage chunk 0 (HBM), hoist u-slice (L2, 128 VGPR), consts ----
    STAGE(0, c0);

    bf16x8 ub[8][4];   // [kt][n]
#pragma unroll
    for (int kt = 0; kt < 8; ++kt)
#pragma unroll
        for (int n = 0; n < 4; ++n)
            ub[kt][n] = *reinterpret_cast<const bf16x8*>(
                u_t + (size_t)(f0w + n * 16 + lc) * E_DIM + kt * 32 + lg * 8);

    float tw_f[4], v_f[4];
#pragma unroll
    for (int n = 0; n < 4; ++n) {
        const int f = f0w + n * 16 + lc;
        tw_f[n] = tw_[b * E_DIM + f];
        v_f[n]  = v[f];
    }

    f32x4 numa = (f32x4){0.f, 0.f, 0.f, 0.f};   // running weighted sum, e=l*4..+3
    float den = 0.f;                             // running denominator (wave rows)

    for (int c = 0; c < NC; ++c) {
        const int cur = c & 1;

        // ---- issue stage c+1; wait ONLY for stage c (counted vmcnt) ----
        if (c + 1 < NC) {
            STAGE(cur ^ 1, c0 + c + 1);
            asm volatile("s_waitcnt vmcnt(8)" ::: "memory");
        } else {
            asm volatile("s_waitcnt vmcnt(0)" ::: "memory");
        }
        __builtin_amdgcn_s_barrier();
        __builtin_amdgcn_sched_barrier(0);

        // ---- K loop on Abuf[cur]: pure LDS + cvt + MFMA  (T5: high prio) ----
        __builtin_amdgcn_s_setprio(1);
        const char* A = (const char*)Abuf[cur];
        f32x4 acc[2][4];
#pragma unroll
        for (int m = 0; m < 2; ++m)
#pragma unroll
            for (int n = 0; n < 4; ++n)
                acc[m][n] = (f32x4){0.f, 0.f, 0.f, 0.f};

#pragma unroll
        for (int kt = 0; kt < 8; ++kt) {
            bf16x8 af[2];
#pragma unroll
            for (int m = 0; m < 2; ++m) {
                const unsigned row = (unsigned)(m * 16 + lc);
                const unsigned s0 = sswz((unsigned)(kt * 8 + lg * 2), row);
                const unsigned s1 = sswz((unsigned)(kt * 8 + lg * 2 + 1), row);
                const f32x4 fa0 = *reinterpret_cast<const f32x4*>(A + row * 1024 + s0 * 16);
                const f32x4 fa1 = *reinterpret_cast<const f32x4*>(A + row * 1024 + s1 * 16);
#pragma unroll
                for (int j = 0; j < 4; ++j) {
                    af[m][j]     = (__bf16)fa0[j];
                    af[m][4 + j] = (__bf16)fa1[j];
                }
            }
#pragma unroll
            for (int n = 0; n < 4; ++n) {
                acc[0][n] = __builtin_amdgcn_mfma_f32_16x16x32_bf16(af[0], ub[kt][n], acc[0][n], 0, 0, 0);
                acc[1][n] = __builtin_amdgcn_mfma_f32_16x16x32_bf16(af[1], ub[kt][n], acc[1][n], 0, 0, 0);
            }
        }
        __builtin_amdgcn_s_setprio(0);

        // ---- gate epilogue: tanh(z+tw)*v, reduce over f (lc classes) ----
        float rs[2][4] = {};   // [m][i]; row = m*16 + lg*4 + i
#pragma unroll
        for (int n = 0; n < 4; ++n)
#pragma unroll
            for (int m = 0; m < 2; ++m)
#pragma unroll
                for (int i = 0; i < 4; ++i)
                    rs[m][i] += fast_tanh(acc[m][n][i] + tw_f[n]) * v_f[n];

#pragma unroll
        for (int off = 1; off < 16; off <<= 1)
#pragma unroll
            for (int m = 0; m < 2; ++m)
#pragma unroll
                for (int i = 0; i < 4; ++i)
                    rs[m][i] += __shfl_xor(rs[m][i], off, 64);

        if (lc == 0) {
#pragma unroll
            for (int m = 0; m < 2; ++m)
#pragma unroll
                for (int i = 0; i < 4; ++i)
                    red[w][m * 16 + lg * 4 + i] = rs[m][i];
        }
        asm volatile("s_waitcnt lgkmcnt(0)" ::: "memory");
        __builtin_amdgcn_s_barrier();   // B2: red ready; all K-loop reads of Abuf[cur] done
        __builtin_amdgcn_sched_barrier(0);

        // ---- fused softmax(no-max) + weighted accumulate, SELF-STAGED rows ----
        // wave w owns rows j*4+w (exactly the rows it stages) -> its own later
        // STAGE is the only writer of these rows, program-ordered after these
        // reads are consumed => no 3rd barrier needed.
#pragma unroll
        for (int j = 0; j < 8; ++j) {
            const unsigned row = (unsigned)(j * 4 + w);
            const float g = red[0][row] + red[1][row] + red[2][row] + red[3][row];
            const float ex = __expf(g);          // |g| <= sum|v_f| ~ 10.3: safe
            den += ex;
            const unsigned ss = sswz((unsigned)l, row);
            const f32x4 hv = *reinterpret_cast<const f32x4*>(A + row * 1024 + ss * 16);
            numa[0] = fmaf(ex, hv[0], numa[0]);
            numa[1] = fmaf(ex, hv[1], numa[1]);
            numa[2] = fmaf(ex, hv[2], numa[2]);
            numa[3] = fmaf(ex, hv[3], numa[3]);
        }
        // no barrier: next STAGE overwrites only this wave's own rows
    }

    // ---- block epilogue: one write of num/den ----
    *reinterpret_cast<f32x4*>(&pacc[w][l * 4]) = numa;
    if (l == 0) dred[w] = den;
    __syncthreads();

    const int nb = SC / NC;                 // blocks per b (8)
    partial[((size_t)b * nb + blockIdx.x) * E_DIM + tid] =
        pacc[0][tid] + pacc[1][tid] + pacc[2][tid] + pacc[3][tid];
    if (tid == 0)
        pd[(size_t)b * nb + blockIdx.x] = dred[0] + dred[1] + dred[2] + dred[3];
#undef STAGE
}

// ---------------- Kernel 2: merge across blocks (no-max softmax: plain sums) ----
__global__ __launch_bounds__(256) void k_combine(const float* __restrict__ partial,
                                                 const float* __restrict__ pd,
                                                 float* __restrict__ out,
                                                 int NB) {
    const int b = blockIdx.x, t = threadIdx.x;
    float den = 0.f;
    for (int k = 0; k < NB; ++k) den += pd[(size_t)b * NB + k];
    float num = 0.f;
    for (int k = 0; k < NB; ++k)
        num += partial[((size_t)b * NB + k) * E_DIM + t];
    out[(size_t)b * E_DIM + t] = num / den;
}

extern "C" void kernel_launch(void* const* d_in, const int* in_sizes, int n_in,
                              void* d_out, int out_size, void* d_ws, size_t ws_size,
                              hipStream_t stream) {
    const float* h     = (const float*)d_in[0];
    const float* theta = (const float*)d_in[1];
    const float* w     = (const float*)d_in[2];
    const float* v     = (const float*)d_in[3];
    const float* u     = (const float*)d_in[4];
    float* out = (float*)d_out;

    const int E = in_sizes[3];              // 256
    const int T = in_sizes[2] / E;          // 100
    const int B = in_sizes[1] / T;          // 64
    const int S = in_sizes[0] / (B * E);    // 2048
    const int SC = S / GM;                  // 64
    const int NB = SC / NC;                 // 8 blocks per b

    float* tw = (float*)d_ws;                                     // [B,E]
    unsigned short* u_t = (unsigned short*)(tw + (size_t)B * E);  // [E,E] bf16
    float* partial = (float*)(u_t + (size_t)E * E);               // [B,NB,E]
    float* pd = partial + (size_t)B * NB * E;                     // [B,NB]

    k_prep<<<dim3(16 + B), dim3(256), 0, stream>>>(u, theta, w, u_t, tw, T);
    k_fused<<<dim3(NB, B), dim3(256), 0, stream>>>(h, u_t, tw, v, partial, pd, S, SC);
    k_combine<<<dim3(B), dim3(256), 0, stream>>>(partial, pd, out, NB);
}

// Round 28
// 53.518 us; speedup vs baseline: 2.9920x; 1.0169x over previous
//
#include <hip/hip_runtime.h>
#include <hip/hip_bf16.h>
#include <math.h>

// vec[b,e] = sum_s softmax_s( tanh(theta@w.T [b,:] + h[b,s,:]@u) @ v ) * h[b,s,e]
// B=64, S=2048, E=256, T=100
// R28 = R27 (54.4us best) with the T5 high-priority region EXTENDED:
//   - setprio(2) on the MFMA K-loop (was 1), setprio(1) through the gate
//     epilogue and wsum (was 0), setprio(0) only around STAGE+vmcnt+barrier.
//     3-level split: stage-wait < epilogue/wsum < MFMA. Register-neutral.
//   - everything else byte-identical to R27/R21: counted vmcnt(8), register-
//     free global_load_lds staging, involution swizzle, u-hoist 128 VGPR,
//     self-staged wsum rows, no-max softmax, register num/den, (2,2) pin.

#define E_DIM 256
#define GM 32        // s-rows per chunk
#define NC 8         // chunks per block

typedef __bf16 bf16x8 __attribute__((ext_vector_type(8)));
typedef float  f32x4  __attribute__((ext_vector_type(4)));

__device__ __forceinline__ unsigned short f2bf(float x) {
    return __builtin_bit_cast(unsigned short, (__bf16)x);
}

// tanh(x) = 1 - 2/(exp(2x)+1); overflow-safe (rcp(inf)=0).
__device__ __forceinline__ float fast_tanh(float x) {
    const float e = __expf(2.0f * x);
    const float r = __builtin_amdgcn_rcpf(e + 1.0f);
    return fmaf(-2.0f, r, 1.0f);
}

// slot swizzle within a 64-slot (16B each) fp32 row: XOR low 4 slot bits
// with row&15. Involution; identical on stage-source and read side.
__device__ __forceinline__ unsigned sswz(unsigned slot, unsigned row) {
    return (slot & 48u) | ((slot & 15u) ^ (row & 15u));
}

// ---------------- Kernel 0 (fused prep): u transpose (coalesced) + theta@w.T ----
__global__ __launch_bounds__(256) void k_prep(const float* __restrict__ u,
                                              const float* __restrict__ theta,
                                              const float* __restrict__ w,
                                              unsigned short* __restrict__ u_t,
                                              float* __restrict__ tw,
                                              int T) {
    if (blockIdx.x < 16) {
        // transpose a 256(e) x 16(f) slab of u into u_t[f][e], coalesced both ways
        __shared__ float tl[256 * 17];   // +1 pad: conflict-free transposed reads
        const int f0 = blockIdx.x * 16;
        const int tid = threadIdx.x;
        const int cl = tid & 15;         // f-col within slab
        const int rw = tid >> 4;         // 0..15
#pragma unroll
        for (int it = 0; it < 16; ++it) {
            const int e = it * 16 + rw;
            tl[e * 17 + cl] = u[(size_t)e * E_DIM + f0 + cl];
        }
        __syncthreads();
        unsigned short outv[16];
#pragma unroll
        for (int j = 0; j < 16; ++j)
            outv[j] = f2bf(tl[(cl * 16 + j) * 17 + rw]);
        *reinterpret_cast<uint4*>(u_t + (size_t)(f0 + rw) * E_DIM + cl * 16) =
            *reinterpret_cast<const uint4*>(outv);
        *reinterpret_cast<uint4*>(u_t + (size_t)(f0 + rw) * E_DIM + cl * 16 + 8) =
            *reinterpret_cast<const uint4*>(outv + 8);
    } else {
        __shared__ float th[128];
        const int b = blockIdx.x - 16;
        const int e = threadIdx.x;
        if (threadIdx.x < T) th[threadIdx.x] = theta[b * T + threadIdx.x];
        __syncthreads();
        float acc = 0.f;
        for (int t = 0; t < T; ++t) acc = fmaf(th[t], w[e * T + t], acc);
        tw[b * E_DIM + e] = acc;
    }
}

// ---------------- Kernel 1 (fused, counted-vmcnt, 3-level setprio) ----------
__global__
__attribute__((amdgpu_flat_work_group_size(256, 256), amdgpu_waves_per_eu(2, 2)))
void k_fused(const float* __restrict__ h,
             const unsigned short* __restrict__ u_t,
             const float* __restrict__ tw_,
             const float* __restrict__ v,
             float* __restrict__ partial,
             float* __restrict__ pd,
             int S, int SC) {
    __shared__ float Abuf[2][GM * E_DIM];   // 2 x 32 KB fp32, slot-swizzled
    __shared__ float red[4][GM];            // 512 B
    __shared__ float pacc[4][E_DIM];        // 4 KB
    __shared__ float dred[4];

    const int b   = blockIdx.y;
    const int c0  = blockIdx.x * NC;        // first chunk for this block
    const int tid = threadIdx.x;
    const int w   = tid >> 6;               // wave 0..3
    const int l   = tid & 63;
    const int lg  = l >> 4;                 // 0..3
    const int lc  = l & 15;                 // 0..15
    const int f0w = w * 64;                 // wave's f-range base

    // stage chunk ch into Abuf[buf]: 8 global_load_lds per WAVE (exact vmcnt
    // count). Wave w stages rows r*4+w. LDS dest linear; source pre-swizzled.
#define STAGE(buf, ch)                                                           \
    {                                                                            \
        const char* hb_ = (const char*)(h + ((size_t)b * S + (size_t)(ch) * GM) * E_DIM); \
        _Pragma("unroll")                                                        \
        for (int r = 0; r < 8; ++r) {                                            \
            const int row = r * 4 + w;                                           \
            const unsigned ss = sswz((unsigned)l, (unsigned)row);                \
            __builtin_amdgcn_global_load_lds(                                    \
                (const __attribute__((address_space(1))) void*)(hb_ + (size_t)row * 1024 + ss * 16), \
                (__attribute__((address_space(3))) void*)((char*)Abuf[buf] + r * 4096 + w * 1024), \
                16, 0, 0);                                                       \
        }                                                                        \
    }

    // ---- prologue: stage chunk 0 (HBM), hoist u-slice (L2, 128 VGPR), consts ----
    STAGE(0, c0);

    bf16x8 ub[8][4];   // [kt][n]
#pragma unroll
    for (int kt = 0; kt < 8; ++kt)
#pragma unroll
        for (int n = 0; n < 4; ++n)
            ub[kt][n] = *reinterpret_cast<const bf16x8*>(
                u_t + (size_t)(f0w + n * 16 + lc) * E_DIM + kt * 32 + lg * 8);

    float tw_f[4], v_f[4];
#pragma unroll
    for (int n = 0; n < 4; ++n) {
        const int f = f0w + n * 16 + lc;
        tw_f[n] = tw_[b * E_DIM + f];
        v_f[n]  = v[f];
    }

    f32x4 numa = (f32x4){0.f, 0.f, 0.f, 0.f};   // running weighted sum, e=l*4..+3
    float den = 0.f;                             // running denominator (wave rows)

    for (int c = 0; c < NC; ++c) {
        const int cur = c & 1;

        // ---- stage phase at prio 0: issue c+1, wait ONLY for stage c ----
        if (c + 1 < NC) {
            STAGE(cur ^ 1, c0 + c + 1);
            asm volatile("s_waitcnt vmcnt(8)" ::: "memory");
        } else {
            asm volatile("s_waitcnt vmcnt(0)" ::: "memory");
        }
        __builtin_amdgcn_s_barrier();
        __builtin_amdgcn_sched_barrier(0);

        // ---- K loop on Abuf[cur]: pure LDS + cvt + MFMA  (prio 2) ----
        __builtin_amdgcn_s_setprio(2);
        const char* A = (const char*)Abuf[cur];
        f32x4 acc[2][4];
#pragma unroll
        for (int m = 0; m < 2; ++m)
#pragma unroll
            for (int n = 0; n < 4; ++n)
                acc[m][n] = (f32x4){0.f, 0.f, 0.f, 0.f};

#pragma unroll
        for (int kt = 0; kt < 8; ++kt) {
            bf16x8 af[2];
#pragma unroll
            for (int m = 0; m < 2; ++m) {
                const unsigned row = (unsigned)(m * 16 + lc);
                const unsigned s0 = sswz((unsigned)(kt * 8 + lg * 2), row);
                const unsigned s1 = sswz((unsigned)(kt * 8 + lg * 2 + 1), row);
                const f32x4 fa0 = *reinterpret_cast<const f32x4*>(A + row * 1024 + s0 * 16);
                const f32x4 fa1 = *reinterpret_cast<const f32x4*>(A + row * 1024 + s1 * 16);
#pragma unroll
                for (int j = 0; j < 4; ++j) {
                    af[m][j]     = (__bf16)fa0[j];
                    af[m][4 + j] = (__bf16)fa1[j];
                }
            }
#pragma unroll
            for (int n = 0; n < 4; ++n) {
                acc[0][n] = __builtin_amdgcn_mfma_f32_16x16x32_bf16(af[0], ub[kt][n], acc[0][n], 0, 0, 0);
                acc[1][n] = __builtin_amdgcn_mfma_f32_16x16x32_bf16(af[1], ub[kt][n], acc[1][n], 0, 0, 0);
            }
        }
        __builtin_amdgcn_s_setprio(1);   // epilogue/wsum at mid priority

        // ---- gate epilogue: tanh(z+tw)*v, reduce over f (lc classes) ----
        float rs[2][4] = {};   // [m][i]; row = m*16 + lg*4 + i
#pragma unroll
        for (int n = 0; n < 4; ++n)
#pragma unroll
            for (int m = 0; m < 2; ++m)
#pragma unroll
                for (int i = 0; i < 4; ++i)
                    rs[m][i] += fast_tanh(acc[m][n][i] + tw_f[n]) * v_f[n];

#pragma unroll
        for (int off = 1; off < 16; off <<= 1)
#pragma unroll
            for (int m = 0; m < 2; ++m)
#pragma unroll
                for (int i = 0; i < 4; ++i)
                    rs[m][i] += __shfl_xor(rs[m][i], off, 64);

        if (lc == 0) {
#pragma unroll
            for (int m = 0; m < 2; ++m)
#pragma unroll
                for (int i = 0; i < 4; ++i)
                    red[w][m * 16 + lg * 4 + i] = rs[m][i];
        }
        asm volatile("s_waitcnt lgkmcnt(0)" ::: "memory");
        __builtin_amdgcn_s_barrier();   // B2: red ready; all K-loop reads of Abuf[cur] done
        __builtin_amdgcn_sched_barrier(0);

        // ---- fused softmax(no-max) + weighted accumulate, SELF-STAGED rows ----
        // wave w owns rows j*4+w (exactly the rows it stages) -> its own later
        // STAGE is the only writer of these rows, program-ordered after these
        // reads are consumed => no 3rd barrier needed.
#pragma unroll
        for (int j = 0; j < 8; ++j) {
            const unsigned row = (unsigned)(j * 4 + w);
            const float g = red[0][row] + red[1][row] + red[2][row] + red[3][row];
            const float ex = __expf(g);          // |g| <= sum|v_f| ~ 10.3: safe
            den += ex;
            const unsigned ss = sswz((unsigned)l, row);
            const f32x4 hv = *reinterpret_cast<const f32x4*>(A + row * 1024 + ss * 16);
            numa[0] = fmaf(ex, hv[0], numa[0]);
            numa[1] = fmaf(ex, hv[1], numa[1]);
            numa[2] = fmaf(ex, hv[2], numa[2]);
            numa[3] = fmaf(ex, hv[3], numa[3]);
        }
        __builtin_amdgcn_s_setprio(0);   // back to low prio for the stage phase
        // no barrier: next STAGE overwrites only this wave's own rows
    }

    // ---- block epilogue: one write of num/den ----
    *reinterpret_cast<f32x4*>(&pacc[w][l * 4]) = numa;
    if (l == 0) dred[w] = den;
    __syncthreads();

    const int nb = SC / NC;                 // blocks per b (8)
    partial[((size_t)b * nb + blockIdx.x) * E_DIM + tid] =
        pacc[0][tid] + pacc[1][tid] + pacc[2][tid] + pacc[3][tid];
    if (tid == 0)
        pd[(size_t)b * nb + blockIdx.x] = dred[0] + dred[1] + dred[2] + dred[3];
#undef STAGE
}

// ---------------- Kernel 2: merge across blocks (no-max softmax: plain sums) ----
__global__ __launch_bounds__(256) void k_combine(const float* __restrict__ partial,
                                                 const float* __restrict__ pd,
                                                 float* __restrict__ out,
                                                 int NB) {
    const int b = blockIdx.x, t = threadIdx.x;
    float den = 0.f;
    for (int k = 0; k < NB; ++k) den += pd[(size_t)b * NB + k];
    float num = 0.f;
    for (int k = 0; k < NB; ++k)
        num += partial[((size_t)b * NB + k) * E_DIM + t];
    out[(size_t)b * E_DIM + t] = num / den;
}

extern "C" void kernel_launch(void* const* d_in, const int* in_sizes, int n_in,
                              void* d_out, int out_size, void* d_ws, size_t ws_size,
                              hipStream_t stream) {
    const float* h     = (const float*)d_in[0];
    const float* theta = (const float*)d_in[1];
    const float* w     = (const float*)d_in[2];
    const float* v     = (const float*)d_in[3];
    const float* u     = (const float*)d_in[4];
    float* out = (float*)d_out;

    const int E = in_sizes[3];              // 256
    const int T = in_sizes[2] / E;          // 100
    const int B = in_sizes[1] / T;          // 64
    const int S = in_sizes[0] / (B * E);    // 2048
    const int SC = S / GM;                  // 64
    const int NB = SC / NC;                 // 8 blocks per b

    float* tw = (float*)d_ws;                                     // [B,E]
    unsigned short* u_t = (unsigned short*)(tw + (size_t)B * E);  // [E,E] bf16
    float* partial = (float*)(u_t + (size_t)E * E);               // [B,NB,E]
    float* pd = partial + (size_t)B * NB * E;                     // [B,NB]

    k_prep<<<dim3(16 + B), dim3(256), 0, stream>>>(u, theta, w, u_t, tw, T);
    k_fused<<<dim3(NB, B), dim3(256), 0, stream>>>(h, u_t, tw, v, partial, pd, S, SC);
    k_combine<<<dim3(B), dim3(256), 0, stream>>>(partial, pd, out, NB);
}